// Round 2
// baseline (253.039 us; speedup 1.0000x reference)
//
#include <hip/hip_runtime.h>
#include <hip/hip_bf16.h>

#define B_ 128
#define S_ 48
#define W_ 12
#define V_ 32000
#define SYM_ 128
#define H_ 256
#define E_ 48
#define R_ 24
#define TM 16

// ---------------------------------------------------------------------------
// Kernel 1: ssum[b,s,c] = sum_w we[story[b,s,w],c]*pe[w,c];  qsum likewise.
// ---------------------------------------------------------------------------
__global__ __launch_bounds__(128) void ssum_kernel(
    const int* __restrict__ story, const int* __restrict__ query,
    const float* __restrict__ we, const float* __restrict__ pe,
    float* __restrict__ ssum, float* __restrict__ qsum)
{
    int i = blockIdx.x;
    int c = threadIdx.x;
    const int* idxp;
    float* outp;
    if (i < B_ * S_) {
        idxp = story + (size_t)i * W_;
        outp = ssum + (size_t)i * SYM_;
    } else {
        int b = i - B_ * S_;
        idxp = query + (size_t)b * W_;
        outp = qsum + (size_t)b * SYM_;
    }
    float acc = 0.f;
#pragma unroll
    for (int w = 0; w < W_; ++w) {
        int id = idxp[w];  // uniform across lanes -> scalar load
        acc = fmaf(we[(size_t)id * SYM_ + c], pe[w * SYM_ + c], acc);
    }
    outp[c] = acc;
}

// ---------------------------------------------------------------------------
// Kernel 2: generic 2-layer tanh MLP, 128->256->OUT, TM rows per block.
// ---------------------------------------------------------------------------
__global__ __launch_bounds__(256) void mlp_kernel(
    const float* __restrict__ x, int M,
    const float* __restrict__ W1e, const float* __restrict__ b1e,
    const float* __restrict__ W2e, const float* __restrict__ b2e,
    int nE,
    const float* __restrict__ W1r, const float* __restrict__ b1r,
    const float* __restrict__ W2r, const float* __restrict__ b2r,
    float* __restrict__ outE,   // [nE][M][48]
    float* __restrict__ outR)   // [nR][M][24]
{
    int m = blockIdx.y;
    int row0 = blockIdx.x * TM;
    const float *W1, *b1, *W2, *b2;
    float* out;
    int OUT;
    if (m < nE) {
        W1 = W1e + (size_t)m * SYM_ * H_;
        b1 = b1e + (size_t)m * H_;
        W2 = W2e + (size_t)m * H_ * E_;
        b2 = b2e + (size_t)m * E_;
        out = outE + (size_t)m * M * E_;
        OUT = E_;
    } else {
        int mr = m - nE;
        W1 = W1r + (size_t)mr * SYM_ * H_;
        b1 = b1r + (size_t)mr * H_;
        W2 = W2r + (size_t)mr * H_ * R_;
        b2 = b2r + (size_t)mr * R_;
        out = outR + (size_t)mr * M * R_;
        OUT = R_;
    }

    int t = threadIdx.x;
    __shared__ __align__(16) float xs[TM][SYM_];
    __shared__ __align__(16) float hs[TM][H_];

    for (int i = t; i < TM * SYM_; i += 256)
        xs[i / SYM_][i % SYM_] = x[(size_t)row0 * SYM_ + i];
    __syncthreads();

    float acc[TM];
#pragma unroll
    for (int row = 0; row < TM; ++row) acc[row] = 0.f;

    const float4* xs4 = reinterpret_cast<const float4*>(&xs[0][0]);
    for (int k4 = 0; k4 < SYM_ / 4; ++k4) {
        float w0 = W1[(size_t)(4 * k4 + 0) * H_ + t];
        float w1 = W1[(size_t)(4 * k4 + 1) * H_ + t];
        float w2 = W1[(size_t)(4 * k4 + 2) * H_ + t];
        float w3 = W1[(size_t)(4 * k4 + 3) * H_ + t];
#pragma unroll
        for (int row = 0; row < TM; ++row) {
            float4 xv = xs4[row * (SYM_ / 4) + k4];
            acc[row] = fmaf(xv.x, w0, fmaf(xv.y, w1, fmaf(xv.z, w2, fmaf(xv.w, w3, acc[row]))));
        }
    }
    float bb = b1[t];
#pragma unroll
    for (int row = 0; row < TM; ++row) hs[row][t] = tanhf(acc[row] + bb);
    __syncthreads();

    for (int idx = t; idx < TM * OUT; idx += 256) {
        int row = idx / OUT;
        int o = idx - row * OUT;
        const float4* hr = reinterpret_cast<const float4*>(&hs[row][0]);
        float a = 0.f;
        for (int k4 = 0; k4 < H_ / 4; ++k4) {
            float4 h = hr[k4];
            a = fmaf(h.x, W2[(size_t)(4 * k4 + 0) * OUT + o],
                fmaf(h.y, W2[(size_t)(4 * k4 + 1) * OUT + o],
                fmaf(h.z, W2[(size_t)(4 * k4 + 2) * OUT + o],
                fmaf(h.w, W2[(size_t)(4 * k4 + 3) * OUT + o], a))));
        }
        out[(size_t)(row0 + row) * OUT + o] = tanhf(a + b2[o]);
    }
}

// ---------------------------------------------------------------------------
// Kernel 3: sequential TPR scan, barrier-free.
// grid (6 f-groups-of-8, B batches), 256 threads = 8 subwaves of 32 lanes.
// Subwave g owns f = blockIdx.x*8+g; lane l<24 owns r=l; lanes 24..31 padded.
// Thread holds TPR[e=0..47, r, f] in registers. Reductions over r are
// __shfl_xor width-32 butterflies. No LDS, no __syncthreads in the loop.
// TPR output layout: [B][E][F=48][R=24].
// ---------------------------------------------------------------------------
__global__ __launch_bounds__(256) void scan_kernel(
    const float* __restrict__ eg,   // [2][B][S][48]
    const float* __restrict__ rg,   // [3][B][S][24]
    float* __restrict__ TPR)        // [B][48][48][24]
{
    const int b = blockIdx.y;
    const int g = threadIdx.x >> 5;
    const int l = threadIdx.x & 31;
    const int f = blockIdx.x * 8 + g;
    const bool act = l < R_;
    const int rc = act ? l : 0;
    const float msk = act ? 1.f : 0.f;

    float T[E_];
#pragma unroll
    for (int e = 0; e < E_; ++e) T[e] = 0.f;

    const size_t bs48 = (size_t)b * S_ * 48;
    const size_t bs24 = (size_t)b * S_ * 24;
    const float* e1g = eg + bs48;
    const float* e2g = eg + (size_t)B_ * S_ * 48 + bs48;
    const float* r1g = rg + bs24;
    const float* r2g = rg + (size_t)B_ * S_ * 24 + bs24;
    const float* r3g = rg + (size_t)2 * B_ * S_ * 24 + bs24;

    // prefetch step 0 per-lane values
    float c_r1 = r1g[rc] * msk;
    float c_r2 = r2g[rc] * msk;
    float c_r3 = r3g[rc] * msk;
    float c_e1f = e1g[f];
    float c_e2f = e2g[f];

    for (int s = 0; s < S_; ++s) {
        // prefetch next step's per-lane values (hidden under the dot/update)
        float n_r1 = 0.f, n_r2 = 0.f, n_r3 = 0.f, n_e1f = 0.f, n_e2f = 0.f;
        if (s + 1 < S_) {
            n_r1 = r1g[(s + 1) * 24 + rc] * msk;
            n_r2 = r2g[(s + 1) * 24 + rc] * msk;
            n_r3 = r3g[(s + 1) * 24 + rc] * msk;
            n_e1f = e1g[(s + 1) * 48 + f];
            n_e2f = e2g[(s + 1) * 48 + f];
        }
        const float* e1p = e1g + s * 48;   // uniform -> scalar loads
        const float* e2p = e2g + s * 48;

        float s1 = 0.f, s2 = 0.f;
#pragma unroll
        for (int e = 0; e < E_; ++e) {
            float a = e1p[e];
            float c = e2p[e];
            s1 = fmaf(a, T[e], s1);
            s2 = fmaf(c, T[e], s2);
        }
        float p0 = c_r1 * s1;   // -> w_hat[f]
        float p1 = c_r2 * s1;   // -> m_hat[f]
        float p2 = c_r3 * s2;   // -> b_hat[f]
#pragma unroll
        for (int d = 16; d >= 1; d >>= 1) {
            p0 += __shfl_xor(p0, d, 32);
            p1 += __shfl_xor(p1, d, 32);
            p2 += __shfl_xor(p2, d, 32);
        }
        float wm = fmaf(c_r1, c_e2f - p0, c_r2 * (p0 - p1)); // write+move at (r,f)
        float bl = c_r3 * (c_e1f - p2);                       // backlink at (r,f)
#pragma unroll
        for (int e = 0; e < E_; ++e) {
            float a = e1p[e];
            float c = e2p[e];
            T[e] = fmaf(a, wm, fmaf(c, bl, T[e]));
        }
        c_r1 = n_r1; c_r2 = n_r2; c_r3 = n_r3; c_e1f = n_e1f; c_e2f = n_e2f;
    }

    if (act) {
#pragma unroll
        for (int e = 0; e < E_; ++e)
            TPR[(((size_t)b * E_ + e) * 48 + f) * 24 + l] = T[e];
    }
}

// ---------------------------------------------------------------------------
// Kernel 4: inference contractions + LayerNorms. One block per batch.
// Thread t: f = t/12, j = t%12; j -> (e-half = j/6, r-quad = j%6).
// float4 reads of TPR rows; partial sums reduced over j in LDS.
// ---------------------------------------------------------------------------
__global__ __launch_bounds__(576) void infer_kernel(
    const float* __restrict__ TPR,   // [B][48][48][24]
    const float* __restrict__ qe1,   // [B][48]
    const float* __restrict__ qr,    // [3][B][24]
    const float* __restrict__ ln_gain, const float* __restrict__ ln_bias,  // [3][48]
    float* __restrict__ isum)        // [B][48]
{
    int b = blockIdx.x;
    int t = threadIdx.x;
    int f = t / 12;
    int j = t % 12;
    int half = j / 6;
    int q4 = j % 6;

    __shared__ float part[48][13];
    __shared__ float xv[48];
    __shared__ float av[48];
    __shared__ float acc3[48];

    const float* Tb = TPR + (size_t)b * E_ * 48 * 24;
    if (t < 48) {
        av[t] = qe1[b * 48 + t];
        acc3[t] = 0.f;
    }
    __syncthreads();

    for (int c = 0; c < 3; ++c) {
        const float* qrc = qr + ((size_t)c * B_ + b) * 24;
        float4 qq = *reinterpret_cast<const float4*>(qrc + 4 * q4);
        float p = 0.f;
        int e0 = half * 24;
#pragma unroll 8
        for (int k = 0; k < 24; ++k) {
            int e = e0 + k;
            float4 v = *reinterpret_cast<const float4*>(Tb + ((size_t)e * 48 + f) * 24 + 4 * q4);
            float d = fmaf(qq.x, v.x, fmaf(qq.y, v.y, fmaf(qq.z, v.z, qq.w * v.w)));
            p = fmaf(av[e], d, p);
        }
        part[f][j] = p;
        __syncthreads();
        if (t < 48) {
            float x = 0.f;
#pragma unroll
            for (int jj = 0; jj < 12; ++jj) x += part[t][jj];
            xv[t] = x;
        }
        __syncthreads();
        if (t < 48) {
            float mu = 0.f;
#pragma unroll
            for (int jj = 0; jj < 48; ++jj) mu += xv[jj];
            mu *= (1.f / 48.f);
            float var = 0.f;
#pragma unroll
            for (int jj = 0; jj < 48; ++jj) {
                float d = xv[jj] - mu;
                var = fmaf(d, d, var);
            }
            var *= (1.f / 48.f);
            float inv = 1.f / sqrtf(var + 1e-6f);
            float o = ln_gain[c * 48 + t] * (xv[t] - mu) * inv + ln_bias[c * 48 + t];
            av[t] = o;
            acc3[t] += o;
        }
        __syncthreads();
    }
    if (t < 48) isum[b * 48 + t] = acc3[t];
}

// ---------------------------------------------------------------------------
// Kernel 5: logits[b,v] = sum_e isum[b,e] * Z[e,v]
// ---------------------------------------------------------------------------
__global__ __launch_bounds__(256) void logits_kernel(
    const float* __restrict__ isum,  // [B][48]
    const float* __restrict__ Z,     // [48][V]
    float* __restrict__ out)         // [B][V]
{
    int v = blockIdx.x * 256 + threadIdx.x;
    int b0 = blockIdx.y * (B_ / 2);
    float z[E_];
#pragma unroll
    for (int e = 0; e < E_; ++e) z[e] = Z[(size_t)e * V_ + v];
    for (int b = b0; b < b0 + B_ / 2; ++b) {
        float a = 0.f;
#pragma unroll
        for (int e = 0; e < E_; ++e) a = fmaf(isum[b * 48 + e], z[e], a);
        out[(size_t)b * V_ + v] = a;
    }
}

// ---------------------------------------------------------------------------
extern "C" void kernel_launch(void* const* d_in, const int* in_sizes, int n_in,
                              void* d_out, int out_size, void* d_ws, size_t ws_size,
                              hipStream_t stream) {
    const int* story  = (const int*)d_in[0];
    const int* query  = (const int*)d_in[1];
    const float* we   = (const float*)d_in[2];
    const float* pe   = (const float*)d_in[3];
    const float* Z    = (const float*)d_in[4];
    const float* ue_W1 = (const float*)d_in[5];
    const float* ue_b1 = (const float*)d_in[6];
    const float* ue_W2 = (const float*)d_in[7];
    const float* ue_b2 = (const float*)d_in[8];
    const float* ur_W1 = (const float*)d_in[9];
    const float* ur_b1 = (const float*)d_in[10];
    const float* ur_W2 = (const float*)d_in[11];
    const float* ur_b2 = (const float*)d_in[12];
    const float* ie_W1 = (const float*)d_in[13];
    const float* ie_b1 = (const float*)d_in[14];
    const float* ie_W2 = (const float*)d_in[15];
    const float* ie_b2 = (const float*)d_in[16];
    const float* ir_W1 = (const float*)d_in[17];
    const float* ir_b1 = (const float*)d_in[18];
    const float* ir_W2 = (const float*)d_in[19];
    const float* ir_b2 = (const float*)d_in[20];
    const float* ln_g  = (const float*)d_in[21];
    const float* ln_b  = (const float*)d_in[22];
    float* out = (float*)d_out;

    float* ws = (float*)d_ws;
    float* ssum = ws;                                  // 786432
    float* qsum = ssum + (size_t)B_ * S_ * SYM_;       // 16384
    float* eout = qsum + (size_t)B_ * SYM_;            // 589824
    float* rout = eout + (size_t)2 * B_ * S_ * E_;     // 442368
    float* qe1  = rout + (size_t)3 * B_ * S_ * R_;     // 6144
    float* qrr  = qe1 + (size_t)B_ * E_;               // 9216
    float* TPR  = qrr + (size_t)3 * B_ * R_;           // 3538944
    float* isum = TPR + (size_t)B_ * E_ * 48 * 24;     // 6144

    ssum_kernel<<<B_ * S_ + B_, 128, 0, stream>>>(story, query, we, pe, ssum, qsum);

    mlp_kernel<<<dim3((B_ * S_) / TM, 5), 256, 0, stream>>>(
        ssum, B_ * S_, ue_W1, ue_b1, ue_W2, ue_b2, 2,
        ur_W1, ur_b1, ur_W2, ur_b2, eout, rout);

    mlp_kernel<<<dim3(B_ / TM, 4), 256, 0, stream>>>(
        qsum, B_, ie_W1, ie_b1, ie_W2, ie_b2, 1,
        ir_W1, ir_b1, ir_W2, ir_b2, qe1, qrr);

    scan_kernel<<<dim3(6, B_), 256, 0, stream>>>(eout, rout, TPR);

    infer_kernel<<<B_, 576, 0, stream>>>(TPR, qe1, qrr, ln_g, ln_b, isum);

    logits_kernel<<<dim3(V_ / 256, 2), 256, 0, stream>>>(isum, Z, out);
}

// Round 3
// 211.553 us; speedup vs baseline: 1.1961x; 1.1961x over previous
//
#include <hip/hip_runtime.h>
#include <hip/hip_bf16.h>

#define B_ 128
#define S_ 48
#define W_ 12
#define V_ 32000
#define SYM_ 128
#define H_ 256
#define E_ 48
#define R_ 24
#define TM 16

typedef float f32x4 __attribute__((ext_vector_type(4)));

// ---------------------------------------------------------------------------
// Kernel 1: ssum[b,s,c] = sum_w we[story[b,s,w],c]*pe[w,c];  qsum likewise.
// ---------------------------------------------------------------------------
__global__ __launch_bounds__(128) void ssum_kernel(
    const int* __restrict__ story, const int* __restrict__ query,
    const float* __restrict__ we, const float* __restrict__ pe,
    float* __restrict__ ssum, float* __restrict__ qsum)
{
    int i = blockIdx.x;
    int c = threadIdx.x;
    const int* idxp;
    float* outp;
    if (i < B_ * S_) {
        idxp = story + (size_t)i * W_;
        outp = ssum + (size_t)i * SYM_;
    } else {
        int b = i - B_ * S_;
        idxp = query + (size_t)b * W_;
        outp = qsum + (size_t)b * SYM_;
    }
    float acc = 0.f;
#pragma unroll
    for (int w = 0; w < W_; ++w) {
        int id = idxp[w];  // uniform across lanes -> scalar load
        acc = fmaf(we[(size_t)id * SYM_ + c], pe[w * SYM_ + c], acc);
    }
    outp[c] = acc;
}

// ---------------------------------------------------------------------------
// Kernel 2: generic 2-layer tanh MLP, 128->256->OUT, TM rows per block.
// ---------------------------------------------------------------------------
__global__ __launch_bounds__(256) void mlp_kernel(
    const float* __restrict__ x, int M,
    const float* __restrict__ W1e, const float* __restrict__ b1e,
    const float* __restrict__ W2e, const float* __restrict__ b2e,
    int nE,
    const float* __restrict__ W1r, const float* __restrict__ b1r,
    const float* __restrict__ W2r, const float* __restrict__ b2r,
    float* __restrict__ outE,   // [nE][M][48]
    float* __restrict__ outR)   // [nR][M][24]
{
    int m = blockIdx.y;
    int row0 = blockIdx.x * TM;
    const float *W1, *b1, *W2, *b2;
    float* out;
    int OUT;
    if (m < nE) {
        W1 = W1e + (size_t)m * SYM_ * H_;
        b1 = b1e + (size_t)m * H_;
        W2 = W2e + (size_t)m * H_ * E_;
        b2 = b2e + (size_t)m * E_;
        out = outE + (size_t)m * M * E_;
        OUT = E_;
    } else {
        int mr = m - nE;
        W1 = W1r + (size_t)mr * SYM_ * H_;
        b1 = b1r + (size_t)mr * H_;
        W2 = W2r + (size_t)mr * H_ * R_;
        b2 = b2r + (size_t)mr * R_;
        out = outR + (size_t)mr * M * R_;
        OUT = R_;
    }

    int t = threadIdx.x;
    __shared__ __align__(16) float xs[TM][SYM_];
    __shared__ __align__(16) float hs[TM][H_];

    for (int i = t; i < TM * SYM_; i += 256)
        xs[i / SYM_][i % SYM_] = x[(size_t)row0 * SYM_ + i];
    __syncthreads();

    float acc[TM];
#pragma unroll
    for (int row = 0; row < TM; ++row) acc[row] = 0.f;

    const float4* xs4 = reinterpret_cast<const float4*>(&xs[0][0]);
    for (int k4 = 0; k4 < SYM_ / 4; ++k4) {
        float w0 = W1[(size_t)(4 * k4 + 0) * H_ + t];
        float w1 = W1[(size_t)(4 * k4 + 1) * H_ + t];
        float w2 = W1[(size_t)(4 * k4 + 2) * H_ + t];
        float w3 = W1[(size_t)(4 * k4 + 3) * H_ + t];
#pragma unroll
        for (int row = 0; row < TM; ++row) {
            float4 xv = xs4[row * (SYM_ / 4) + k4];
            acc[row] = fmaf(xv.x, w0, fmaf(xv.y, w1, fmaf(xv.z, w2, fmaf(xv.w, w3, acc[row]))));
        }
    }
    float bb = b1[t];
#pragma unroll
    for (int row = 0; row < TM; ++row) hs[row][t] = tanhf(acc[row] + bb);
    __syncthreads();

    for (int idx = t; idx < TM * OUT; idx += 256) {
        int row = idx / OUT;
        int o = idx - row * OUT;
        const float4* hr = reinterpret_cast<const float4*>(&hs[row][0]);
        float a = 0.f;
        for (int k4 = 0; k4 < H_ / 4; ++k4) {
            float4 h = hr[k4];
            a = fmaf(h.x, W2[(size_t)(4 * k4 + 0) * OUT + o],
                fmaf(h.y, W2[(size_t)(4 * k4 + 1) * OUT + o],
                fmaf(h.z, W2[(size_t)(4 * k4 + 2) * OUT + o],
                fmaf(h.w, W2[(size_t)(4 * k4 + 3) * OUT + o], a))));
        }
        out[(size_t)(row0 + row) * OUT + o] = tanhf(a + b2[o]);
    }
}

// ---------------------------------------------------------------------------
// Kernel 3: sequential TPR scan, barrier-free, accumulator FORCED into VGPRs
// via 12 named ext_vector_type(4) values (rule #20: no runtime-indexed array).
// grid (6 f-groups-of-8, B batches), 256 threads = 8 subwaves of 32 lanes.
// Subwave g owns f = blockIdx.x*8+g; lane l<24 owns r=l; lanes 24..31 padded.
// Reductions over r are __shfl_xor width-32 butterflies. No LDS/barriers.
// TPR output layout: [B][E][F=48][R=24].
// ---------------------------------------------------------------------------
__global__ __launch_bounds__(256) void scan_kernel(
    const float* __restrict__ eg,   // [2][B][S][48]
    const float* __restrict__ rg,   // [3][B][S][24]
    float* __restrict__ TPR)        // [B][48][48][24]
{
    const int b = blockIdx.y;
    const int g = threadIdx.x >> 5;
    const int l = threadIdx.x & 31;
    const int f = blockIdx.x * 8 + g;
    const bool act = l < R_;
    const int rc = act ? l : 0;
    const float msk = act ? 1.f : 0.f;

    f32x4 T0 = {0.f, 0.f, 0.f, 0.f};
    f32x4 T1 = T0, T2 = T0, T3 = T0, T4 = T0, T5 = T0,
          T6 = T0, T7 = T0, T8 = T0, T9 = T0, T10 = T0, T11 = T0;

    const size_t bs48 = (size_t)b * S_ * 48;
    const size_t bs24 = (size_t)b * S_ * 24;
    const float* e1g = eg + bs48;
    const float* e2g = eg + (size_t)B_ * S_ * 48 + bs48;
    const float* r1g = rg + bs24;
    const float* r2g = rg + (size_t)B_ * S_ * 24 + bs24;
    const float* r3g = rg + (size_t)2 * B_ * S_ * 24 + bs24;

    for (int s = 0; s < S_; ++s) {
        // per-lane role values (issued early; latency hidden under the dot)
        float r1v = r1g[s * 24 + rc] * msk;
        float r2v = r2g[s * 24 + rc] * msk;
        float r3v = r3g[s * 24 + rc] * msk;
        const f32x4* e1q = reinterpret_cast<const f32x4*>(e1g + s * 48);  // uniform -> s_load
        const f32x4* e2q = reinterpret_cast<const f32x4*>(e2g + s * 48);
        float e1f = (e1g + s * 48)[f];
        float e2f = (e2g + s * 48)[f];

        f32x4 s1v = {0.f, 0.f, 0.f, 0.f};
        f32x4 s2v = s1v;
#define DOTI(i) { f32x4 a = e1q[i]; f32x4 c = e2q[i]; \
        s1v = __builtin_elementwise_fma(a, T##i, s1v); \
        s2v = __builtin_elementwise_fma(c, T##i, s2v); }
        DOTI(0) DOTI(1) DOTI(2) DOTI(3) DOTI(4) DOTI(5)
        DOTI(6) DOTI(7) DOTI(8) DOTI(9) DOTI(10) DOTI(11)
#undef DOTI
        float s1 = (s1v[0] + s1v[1]) + (s1v[2] + s1v[3]);
        float s2 = (s2v[0] + s2v[1]) + (s2v[2] + s2v[3]);

        float p0 = r1v * s1;   // -> w_hat[f]
        float p1 = r2v * s1;   // -> m_hat[f]
        float p2 = r3v * s2;   // -> b_hat[f]
#pragma unroll
        for (int d = 16; d >= 1; d >>= 1) {
            p0 += __shfl_xor(p0, d, 32);
            p1 += __shfl_xor(p1, d, 32);
            p2 += __shfl_xor(p2, d, 32);
        }
        float wm = fmaf(r1v, e2f - p0, r2v * (p0 - p1)); // write+move at (r,f)
        float bl = r3v * (e1f - p2);                      // backlink at (r,f)
        f32x4 w4 = {wm, wm, wm, wm};
        f32x4 b4 = {bl, bl, bl, bl};
#define UPDI(i) { f32x4 a = e1q[i]; f32x4 c = e2q[i]; \
        T##i = __builtin_elementwise_fma(a, w4, __builtin_elementwise_fma(c, b4, T##i)); }
        UPDI(0) UPDI(1) UPDI(2) UPDI(3) UPDI(4) UPDI(5)
        UPDI(6) UPDI(7) UPDI(8) UPDI(9) UPDI(10) UPDI(11)
#undef UPDI
    }

    if (act) {
        float* outp = TPR + ((size_t)b * E_ * 48 + f) * 24 + l;
#define STI(i) { f32x4 v = T##i; \
        outp[(size_t)(4 * i + 0) * 48 * 24] = v[0]; \
        outp[(size_t)(4 * i + 1) * 48 * 24] = v[1]; \
        outp[(size_t)(4 * i + 2) * 48 * 24] = v[2]; \
        outp[(size_t)(4 * i + 3) * 48 * 24] = v[3]; }
        STI(0) STI(1) STI(2) STI(3) STI(4) STI(5)
        STI(6) STI(7) STI(8) STI(9) STI(10) STI(11)
#undef STI
    }
}

// ---------------------------------------------------------------------------
// Kernel 4: inference contractions + LayerNorms. One block per batch.
// ---------------------------------------------------------------------------
__global__ __launch_bounds__(576) void infer_kernel(
    const float* __restrict__ TPR,   // [B][48][48][24]
    const float* __restrict__ qe1,   // [B][48]
    const float* __restrict__ qr,    // [3][B][24]
    const float* __restrict__ ln_gain, const float* __restrict__ ln_bias,  // [3][48]
    float* __restrict__ isum)        // [B][48]
{
    int b = blockIdx.x;
    int t = threadIdx.x;
    int f = t / 12;
    int j = t % 12;
    int half = j / 6;
    int q4 = j % 6;

    __shared__ float part[48][13];
    __shared__ float xv[48];
    __shared__ float av[48];
    __shared__ float acc3[48];

    const float* Tb = TPR + (size_t)b * E_ * 48 * 24;
    if (t < 48) {
        av[t] = qe1[b * 48 + t];
        acc3[t] = 0.f;
    }
    __syncthreads();

    for (int c = 0; c < 3; ++c) {
        const float* qrc = qr + ((size_t)c * B_ + b) * 24;
        float4 qq = *reinterpret_cast<const float4*>(qrc + 4 * q4);
        float p = 0.f;
        int e0 = half * 24;
#pragma unroll 8
        for (int k = 0; k < 24; ++k) {
            int e = e0 + k;
            float4 v = *reinterpret_cast<const float4*>(Tb + ((size_t)e * 48 + f) * 24 + 4 * q4);
            float d = fmaf(qq.x, v.x, fmaf(qq.y, v.y, fmaf(qq.z, v.z, qq.w * v.w)));
            p = fmaf(av[e], d, p);
        }
        part[f][j] = p;
        __syncthreads();
        if (t < 48) {
            float x = 0.f;
#pragma unroll
            for (int jj = 0; jj < 12; ++jj) x += part[t][jj];
            xv[t] = x;
        }
        __syncthreads();
        if (t < 48) {
            float mu = 0.f;
#pragma unroll
            for (int jj = 0; jj < 48; ++jj) mu += xv[jj];
            mu *= (1.f / 48.f);
            float var = 0.f;
#pragma unroll
            for (int jj = 0; jj < 48; ++jj) {
                float d = xv[jj] - mu;
                var = fmaf(d, d, var);
            }
            var *= (1.f / 48.f);
            float inv = 1.f / sqrtf(var + 1e-6f);
            float o = ln_gain[c * 48 + t] * (xv[t] - mu) * inv + ln_bias[c * 48 + t];
            av[t] = o;
            acc3[t] += o;
        }
        __syncthreads();
    }
    if (t < 48) isum[b * 48 + t] = acc3[t];
}

// ---------------------------------------------------------------------------
// Kernel 5: logits[b,v] = sum_e isum[b,e] * Z[e,v]
// ---------------------------------------------------------------------------
__global__ __launch_bounds__(256) void logits_kernel(
    const float* __restrict__ isum,  // [B][48]
    const float* __restrict__ Z,     // [48][V]
    float* __restrict__ out)         // [B][V]
{
    int v = blockIdx.x * 256 + threadIdx.x;
    int b0 = blockIdx.y * (B_ / 4);
    float z[E_];
#pragma unroll
    for (int e = 0; e < E_; ++e) z[e] = Z[(size_t)e * V_ + v];
    for (int b = b0; b < b0 + B_ / 4; ++b) {
        float a = 0.f;
#pragma unroll
        for (int e = 0; e < E_; ++e) a = fmaf(isum[b * 48 + e], z[e], a);
        out[(size_t)b * V_ + v] = a;
    }
}

// ---------------------------------------------------------------------------
extern "C" void kernel_launch(void* const* d_in, const int* in_sizes, int n_in,
                              void* d_out, int out_size, void* d_ws, size_t ws_size,
                              hipStream_t stream) {
    const int* story  = (const int*)d_in[0];
    const int* query  = (const int*)d_in[1];
    const float* we   = (const float*)d_in[2];
    const float* pe   = (const float*)d_in[3];
    const float* Z    = (const float*)d_in[4];
    const float* ue_W1 = (const float*)d_in[5];
    const float* ue_b1 = (const float*)d_in[6];
    const float* ue_W2 = (const float*)d_in[7];
    const float* ue_b2 = (const float*)d_in[8];
    const float* ur_W1 = (const float*)d_in[9];
    const float* ur_b1 = (const float*)d_in[10];
    const float* ur_W2 = (const float*)d_in[11];
    const float* ur_b2 = (const float*)d_in[12];
    const float* ie_W1 = (const float*)d_in[13];
    const float* ie_b1 = (const float*)d_in[14];
    const float* ie_W2 = (const float*)d_in[15];
    const float* ie_b2 = (const float*)d_in[16];
    const float* ir_W1 = (const float*)d_in[17];
    const float* ir_b1 = (const float*)d_in[18];
    const float* ir_W2 = (const float*)d_in[19];
    const float* ir_b2 = (const float*)d_in[20];
    const float* ln_g  = (const float*)d_in[21];
    const float* ln_b  = (const float*)d_in[22];
    float* out = (float*)d_out;

    float* ws = (float*)d_ws;
    float* ssum = ws;                                  // 786432
    float* qsum = ssum + (size_t)B_ * S_ * SYM_;       // 16384
    float* eout = qsum + (size_t)B_ * SYM_;            // 589824
    float* rout = eout + (size_t)2 * B_ * S_ * E_;     // 442368
    float* qe1  = rout + (size_t)3 * B_ * S_ * R_;     // 6144
    float* qrr  = qe1 + (size_t)B_ * E_;               // 9216
    float* TPR  = qrr + (size_t)3 * B_ * R_;           // 3538944
    float* isum = TPR + (size_t)B_ * E_ * 48 * 24;     // 6144

    ssum_kernel<<<B_ * S_ + B_, 128, 0, stream>>>(story, query, we, pe, ssum, qsum);

    mlp_kernel<<<dim3((B_ * S_) / TM, 5), 256, 0, stream>>>(
        ssum, B_ * S_, ue_W1, ue_b1, ue_W2, ue_b2, 2,
        ur_W1, ur_b1, ur_W2, ur_b2, eout, rout);

    mlp_kernel<<<dim3(B_ / TM, 4), 256, 0, stream>>>(
        qsum, B_, ie_W1, ie_b1, ie_W2, ie_b2, 1,
        ir_W1, ir_b1, ir_W2, ir_b2, qe1, qrr);

    scan_kernel<<<dim3(6, B_), 256, 0, stream>>>(eout, rout, TPR);

    infer_kernel<<<B_, 576, 0, stream>>>(TPR, qe1, qrr, ln_g, ln_b, isum);

    logits_kernel<<<dim3(V_ / 256, 4), 256, 0, stream>>>(isum, Z, out);
}

// Round 4
// 206.197 us; speedup vs baseline: 1.2272x; 1.0260x over previous
//
#include <hip/hip_runtime.h>
#include <hip/hip_bf16.h>

#define B_ 128
#define S_ 48
#define W_ 12
#define V_ 32000
#define SYM_ 128
#define H_ 256
#define E_ 48
#define R_ 24
#define TM 16

typedef float f32x4 __attribute__((ext_vector_type(4)));

__device__ __forceinline__ float4 fma4(float s, float4 w, float4 a) {
    a.x = fmaf(s, w.x, a.x); a.y = fmaf(s, w.y, a.y);
    a.z = fmaf(s, w.z, a.z); a.w = fmaf(s, w.w, a.w);
    return a;
}

// ---------------------------------------------------------------------------
// Kernel 1: ssum[b,s,c] = sum_w we[story[b,s,w],c]*pe[w,c];  qsum likewise.
// ---------------------------------------------------------------------------
__global__ __launch_bounds__(128) void ssum_kernel(
    const int* __restrict__ story, const int* __restrict__ query,
    const float* __restrict__ we, const float* __restrict__ pe,
    float* __restrict__ ssum, float* __restrict__ qsum)
{
    int i = blockIdx.x;
    int c = threadIdx.x;
    const int* idxp;
    float* outp;
    if (i < B_ * S_) {
        idxp = story + (size_t)i * W_;
        outp = ssum + (size_t)i * SYM_;
    } else {
        int b = i - B_ * S_;
        idxp = query + (size_t)b * W_;
        outp = qsum + (size_t)b * SYM_;
    }
    float acc = 0.f;
#pragma unroll
    for (int w = 0; w < W_; ++w) {
        int id = idxp[w];  // uniform across lanes -> scalar load
        acc = fmaf(we[(size_t)id * SYM_ + c], pe[w * SYM_ + c], acc);
    }
    outp[c] = acc;
}

// ---------------------------------------------------------------------------
// Kernel 2: 2-layer tanh MLP, 128->256->OUT, TM=16 rows per block.
// Layer 1: register-tiled 4x4 per thread (rq=t>>6 row-quad, cq=t&63 col-quad):
//   per k4: 4 broadcast LDS b128 x-reads + 4 coalesced global W1 float4 + 64 FMA.
// Layer 2: thread (row, col-quad) computes 1x4; hs padded to 260-float rows
//   so the 6 concurrent row addresses hit distinct bank quads.
// ---------------------------------------------------------------------------
__global__ __launch_bounds__(256) void mlp_kernel(
    const float* __restrict__ x, int M,
    const float* __restrict__ W1e, const float* __restrict__ b1e,
    const float* __restrict__ W2e, const float* __restrict__ b2e,
    int nE,
    const float* __restrict__ W1r, const float* __restrict__ b1r,
    const float* __restrict__ W2r, const float* __restrict__ b2r,
    float* __restrict__ outE,   // [nE][M][48]
    float* __restrict__ outR)   // [nR][M][24]
{
    int m = blockIdx.y;
    int row0 = blockIdx.x * TM;
    const float *W1, *b1, *W2, *b2;
    float* out;
    int OUT;
    if (m < nE) {
        W1 = W1e + (size_t)m * SYM_ * H_;
        b1 = b1e + (size_t)m * H_;
        W2 = W2e + (size_t)m * H_ * E_;
        b2 = b2e + (size_t)m * E_;
        out = outE + (size_t)m * M * E_;
        OUT = E_;
    } else {
        int mr = m - nE;
        W1 = W1r + (size_t)mr * SYM_ * H_;
        b1 = b1r + (size_t)mr * H_;
        W2 = W2r + (size_t)mr * H_ * R_;
        b2 = b2r + (size_t)mr * R_;
        out = outR + (size_t)mr * M * R_;
        OUT = R_;
    }

    int t = threadIdx.x;
    __shared__ __align__(16) float4 xs4[TM][SYM_ / 4];  // [16][32] = 8 KB
    __shared__ __align__(16) float4 hs4[TM * 65];       // row stride 65 quads, 16.6 KB

    {
        const float4* xsrc = reinterpret_cast<const float4*>(x + (size_t)row0 * SYM_);
        for (int i = t; i < TM * (SYM_ / 4); i += 256)
            xs4[i >> 5][i & 31] = xsrc[i];
    }
    __syncthreads();

    // ---- layer 1 ----
    const int cq = t & 63;
    const int rq = t >> 6;
    const float4* W1_4 = reinterpret_cast<const float4*>(W1);  // [128][64]
    float4 a0 = {0, 0, 0, 0}, a1 = a0, a2 = a0, a3 = a0;
    for (int k4 = 0; k4 < SYM_ / 4; ++k4) {
        float4 w0 = W1_4[(size_t)(4 * k4 + 0) * (H_ / 4) + cq];
        float4 w1 = W1_4[(size_t)(4 * k4 + 1) * (H_ / 4) + cq];
        float4 w2 = W1_4[(size_t)(4 * k4 + 2) * (H_ / 4) + cq];
        float4 w3 = W1_4[(size_t)(4 * k4 + 3) * (H_ / 4) + cq];
        float4 x0 = xs4[4 * rq + 0][k4];
        float4 x1 = xs4[4 * rq + 1][k4];
        float4 x2 = xs4[4 * rq + 2][k4];
        float4 x3 = xs4[4 * rq + 3][k4];
        a0 = fma4(x0.x, w0, fma4(x0.y, w1, fma4(x0.z, w2, fma4(x0.w, w3, a0))));
        a1 = fma4(x1.x, w0, fma4(x1.y, w1, fma4(x1.z, w2, fma4(x1.w, w3, a1))));
        a2 = fma4(x2.x, w0, fma4(x2.y, w1, fma4(x2.z, w2, fma4(x2.w, w3, a2))));
        a3 = fma4(x3.x, w0, fma4(x3.y, w1, fma4(x3.z, w2, fma4(x3.w, w3, a3))));
    }
    {
        float4 bb = reinterpret_cast<const float4*>(b1)[cq];
        float4 v;
        v.x = tanhf(a0.x + bb.x); v.y = tanhf(a0.y + bb.y);
        v.z = tanhf(a0.z + bb.z); v.w = tanhf(a0.w + bb.w);
        hs4[(4 * rq + 0) * 65 + cq] = v;
        v.x = tanhf(a1.x + bb.x); v.y = tanhf(a1.y + bb.y);
        v.z = tanhf(a1.z + bb.z); v.w = tanhf(a1.w + bb.w);
        hs4[(4 * rq + 1) * 65 + cq] = v;
        v.x = tanhf(a2.x + bb.x); v.y = tanhf(a2.y + bb.y);
        v.z = tanhf(a2.z + bb.z); v.w = tanhf(a2.w + bb.w);
        hs4[(4 * rq + 2) * 65 + cq] = v;
        v.x = tanhf(a3.x + bb.x); v.y = tanhf(a3.y + bb.y);
        v.z = tanhf(a3.z + bb.z); v.w = tanhf(a3.w + bb.w);
        hs4[(4 * rq + 3) * 65 + cq] = v;
    }
    __syncthreads();

    // ---- layer 2 ----
    const int nq = OUT / 4;                 // 12 or 6
    if (t < TM * nq) {
        int row = t / nq, q = t - row * nq;
        const float4* W2_4 = reinterpret_cast<const float4*>(W2);  // [256][nq]
        float4 a = {0, 0, 0, 0};
        for (int k4 = 0; k4 < H_ / 4; ++k4) {
            float4 h = hs4[row * 65 + k4];
            float4 w0 = W2_4[(size_t)(4 * k4 + 0) * nq + q];
            float4 w1 = W2_4[(size_t)(4 * k4 + 1) * nq + q];
            float4 w2 = W2_4[(size_t)(4 * k4 + 2) * nq + q];
            float4 w3 = W2_4[(size_t)(4 * k4 + 3) * nq + q];
            a = fma4(h.x, w0, fma4(h.y, w1, fma4(h.z, w2, fma4(h.w, w3, a))));
        }
        float4 bv = reinterpret_cast<const float4*>(b2)[q];
        float4 o;
        o.x = tanhf(a.x + bv.x); o.y = tanhf(a.y + bv.y);
        o.z = tanhf(a.z + bv.z); o.w = tanhf(a.w + bv.w);
        reinterpret_cast<float4*>(out + (size_t)(row0 + row) * OUT)[q] = o;
    }
}

// ---------------------------------------------------------------------------
// Kernel 3: sequential TPR scan, barrier-free, accumulator in named f32x4s.
// grid (6, B), 256 threads = 8 subwaves of 32; lane<24 owns r, lanes 24-31 pad.
// ---------------------------------------------------------------------------
__global__ __launch_bounds__(256) void scan_kernel(
    const float* __restrict__ eg,   // [2][B][S][48]
    const float* __restrict__ rg,   // [3][B][S][24]
    float* __restrict__ TPR)        // [B][48][48][24]
{
    const int b = blockIdx.y;
    const int g = threadIdx.x >> 5;
    const int l = threadIdx.x & 31;
    const int f = blockIdx.x * 8 + g;
    const bool act = l < R_;
    const int rc = act ? l : 0;
    const float msk = act ? 1.f : 0.f;

    f32x4 T0 = {0.f, 0.f, 0.f, 0.f};
    f32x4 T1 = T0, T2 = T0, T3 = T0, T4 = T0, T5 = T0,
          T6 = T0, T7 = T0, T8 = T0, T9 = T0, T10 = T0, T11 = T0;

    const size_t bs48 = (size_t)b * S_ * 48;
    const size_t bs24 = (size_t)b * S_ * 24;
    const float* e1g = eg + bs48;
    const float* e2g = eg + (size_t)B_ * S_ * 48 + bs48;
    const float* r1g = rg + bs24;
    const float* r2g = rg + (size_t)B_ * S_ * 24 + bs24;
    const float* r3g = rg + (size_t)2 * B_ * S_ * 24 + bs24;

    for (int s = 0; s < S_; ++s) {
        float r1v = r1g[s * 24 + rc] * msk;
        float r2v = r2g[s * 24 + rc] * msk;
        float r3v = r3g[s * 24 + rc] * msk;
        const f32x4* e1q = reinterpret_cast<const f32x4*>(e1g + s * 48);  // uniform -> s_load
        const f32x4* e2q = reinterpret_cast<const f32x4*>(e2g + s * 48);
        float e1f = (e1g + s * 48)[f];
        float e2f = (e2g + s * 48)[f];

        f32x4 s1v = {0.f, 0.f, 0.f, 0.f};
        f32x4 s2v = s1v;
#define DOTI(i) { f32x4 a = e1q[i]; f32x4 c = e2q[i]; \
        s1v = __builtin_elementwise_fma(a, T##i, s1v); \
        s2v = __builtin_elementwise_fma(c, T##i, s2v); }
        DOTI(0) DOTI(1) DOTI(2) DOTI(3) DOTI(4) DOTI(5)
        DOTI(6) DOTI(7) DOTI(8) DOTI(9) DOTI(10) DOTI(11)
#undef DOTI
        float s1 = (s1v[0] + s1v[1]) + (s1v[2] + s1v[3]);
        float s2 = (s2v[0] + s2v[1]) + (s2v[2] + s2v[3]);

        float p0 = r1v * s1;
        float p1 = r2v * s1;
        float p2 = r3v * s2;
#pragma unroll
        for (int d = 16; d >= 1; d >>= 1) {
            p0 += __shfl_xor(p0, d, 32);
            p1 += __shfl_xor(p1, d, 32);
            p2 += __shfl_xor(p2, d, 32);
        }
        float wm = fmaf(r1v, e2f - p0, r2v * (p0 - p1));
        float bl = r3v * (e1f - p2);
        f32x4 w4 = {wm, wm, wm, wm};
        f32x4 b4 = {bl, bl, bl, bl};
#define UPDI(i) { f32x4 a = e1q[i]; f32x4 c = e2q[i]; \
        T##i = __builtin_elementwise_fma(a, w4, __builtin_elementwise_fma(c, b4, T##i)); }
        UPDI(0) UPDI(1) UPDI(2) UPDI(3) UPDI(4) UPDI(5)
        UPDI(6) UPDI(7) UPDI(8) UPDI(9) UPDI(10) UPDI(11)
#undef UPDI
    }

    if (act) {
        float* outp = TPR + ((size_t)b * E_ * 48 + f) * 24 + l;
#define STI(i) { f32x4 v = T##i; \
        outp[(size_t)(4 * i + 0) * 48 * 24] = v[0]; \
        outp[(size_t)(4 * i + 1) * 48 * 24] = v[1]; \
        outp[(size_t)(4 * i + 2) * 48 * 24] = v[2]; \
        outp[(size_t)(4 * i + 3) * 48 * 24] = v[3]; }
        STI(0) STI(1) STI(2) STI(3) STI(4) STI(5)
        STI(6) STI(7) STI(8) STI(9) STI(10) STI(11)
#undef STI
    }
}

// ---------------------------------------------------------------------------
// Kernel 4: inference contractions + LayerNorms. One block per batch.
// ---------------------------------------------------------------------------
__global__ __launch_bounds__(576) void infer_kernel(
    const float* __restrict__ TPR,   // [B][48][48][24]
    const float* __restrict__ qe1,   // [B][48]
    const float* __restrict__ qr,    // [3][B][24]
    const float* __restrict__ ln_gain, const float* __restrict__ ln_bias,  // [3][48]
    float* __restrict__ isum)        // [B][48]
{
    int b = blockIdx.x;
    int t = threadIdx.x;
    int f = t / 12;
    int j = t % 12;
    int half = j / 6;
    int q4 = j % 6;

    __shared__ float part[48][13];
    __shared__ float xv[48];
    __shared__ float av[48];
    __shared__ float acc3[48];

    const float* Tb = TPR + (size_t)b * E_ * 48 * 24;
    if (t < 48) {
        av[t] = qe1[b * 48 + t];
        acc3[t] = 0.f;
    }
    __syncthreads();

    for (int c = 0; c < 3; ++c) {
        const float* qrc = qr + ((size_t)c * B_ + b) * 24;
        float4 qq = *reinterpret_cast<const float4*>(qrc + 4 * q4);
        float p = 0.f;
        int e0 = half * 24;
#pragma unroll 8
        for (int k = 0; k < 24; ++k) {
            int e = e0 + k;
            float4 v = *reinterpret_cast<const float4*>(Tb + ((size_t)e * 48 + f) * 24 + 4 * q4);
            float d = fmaf(qq.x, v.x, fmaf(qq.y, v.y, fmaf(qq.z, v.z, qq.w * v.w)));
            p = fmaf(av[e], d, p);
        }
        part[f][j] = p;
        __syncthreads();
        if (t < 48) {
            float x = 0.f;
#pragma unroll
            for (int jj = 0; jj < 12; ++jj) x += part[t][jj];
            xv[t] = x;
        }
        __syncthreads();
        if (t < 48) {
            float mu = 0.f;
#pragma unroll
            for (int jj = 0; jj < 48; ++jj) mu += xv[jj];
            mu *= (1.f / 48.f);
            float var = 0.f;
#pragma unroll
            for (int jj = 0; jj < 48; ++jj) {
                float d = xv[jj] - mu;
                var = fmaf(d, d, var);
            }
            var *= (1.f / 48.f);
            float inv = 1.f / sqrtf(var + 1e-6f);
            float o = ln_gain[c * 48 + t] * (xv[t] - mu) * inv + ln_bias[c * 48 + t];
            av[t] = o;
            acc3[t] += o;
        }
        __syncthreads();
    }
    if (t < 48) isum[b * 48 + t] = acc3[t];
}

// ---------------------------------------------------------------------------
// Kernel 5: logits[b,v] = sum_e isum[b,e] * Z[e,v]
// ---------------------------------------------------------------------------
__global__ __launch_bounds__(256) void logits_kernel(
    const float* __restrict__ isum,  // [B][48]
    const float* __restrict__ Z,     // [48][V]
    float* __restrict__ out)         // [B][V]
{
    int v = blockIdx.x * 256 + threadIdx.x;
    int b0 = blockIdx.y * (B_ / 4);
    float z[E_];
#pragma unroll
    for (int e = 0; e < E_; ++e) z[e] = Z[(size_t)e * V_ + v];
    for (int b = b0; b < b0 + B_ / 4; ++b) {
        float a = 0.f;
#pragma unroll
        for (int e = 0; e < E_; ++e) a = fmaf(isum[b * 48 + e], z[e], a);
        out[(size_t)b * V_ + v] = a;
    }
}

// ---------------------------------------------------------------------------
extern "C" void kernel_launch(void* const* d_in, const int* in_sizes, int n_in,
                              void* d_out, int out_size, void* d_ws, size_t ws_size,
                              hipStream_t stream) {
    const int* story  = (const int*)d_in[0];
    const int* query  = (const int*)d_in[1];
    const float* we   = (const float*)d_in[2];
    const float* pe   = (const float*)d_in[3];
    const float* Z    = (const float*)d_in[4];
    const float* ue_W1 = (const float*)d_in[5];
    const float* ue_b1 = (const float*)d_in[6];
    const float* ue_W2 = (const float*)d_in[7];
    const float* ue_b2 = (const float*)d_in[8];
    const float* ur_W1 = (const float*)d_in[9];
    const float* ur_b1 = (const float*)d_in[10];
    const float* ur_W2 = (const float*)d_in[11];
    const float* ur_b2 = (const float*)d_in[12];
    const float* ie_W1 = (const float*)d_in[13];
    const float* ie_b1 = (const float*)d_in[14];
    const float* ie_W2 = (const float*)d_in[15];
    const float* ie_b2 = (const float*)d_in[16];
    const float* ir_W1 = (const float*)d_in[17];
    const float* ir_b1 = (const float*)d_in[18];
    const float* ir_W2 = (const float*)d_in[19];
    const float* ir_b2 = (const float*)d_in[20];
    const float* ln_g  = (const float*)d_in[21];
    const float* ln_b  = (const float*)d_in[22];
    float* out = (float*)d_out;

    float* ws = (float*)d_ws;
    float* ssum = ws;                                  // 786432
    float* qsum = ssum + (size_t)B_ * S_ * SYM_;       // 16384
    float* eout = qsum + (size_t)B_ * SYM_;            // 589824
    float* rout = eout + (size_t)2 * B_ * S_ * E_;     // 442368
    float* qe1  = rout + (size_t)3 * B_ * S_ * R_;     // 6144
    float* qrr  = qe1 + (size_t)B_ * E_;               // 9216
    float* TPR  = qrr + (size_t)3 * B_ * R_;           // 3538944
    float* isum = TPR + (size_t)B_ * E_ * 48 * 24;     // 6144

    ssum_kernel<<<B_ * S_ + B_, 128, 0, stream>>>(story, query, we, pe, ssum, qsum);

    mlp_kernel<<<dim3((B_ * S_) / TM, 5), 256, 0, stream>>>(
        ssum, B_ * S_, ue_W1, ue_b1, ue_W2, ue_b2, 2,
        ur_W1, ur_b1, ur_W2, ur_b2, eout, rout);

    mlp_kernel<<<dim3(B_ / TM, 4), 256, 0, stream>>>(
        qsum, B_, ie_W1, ie_b1, ie_W2, ie_b2, 1,
        ir_W1, ir_b1, ir_W2, ir_b2, qe1, qrr);

    scan_kernel<<<dim3(6, B_), 256, 0, stream>>>(eout, rout, TPR);

    infer_kernel<<<B_, 576, 0, stream>>>(TPR, qe1, qrr, ln_g, ln_b, isum);

    logits_kernel<<<dim3(V_ / 256, 4), 256, 0, stream>>>(isum, Z, out);
}